// Round 12
// baseline (496.076 us; speedup 1.0000x reference)
//
#include <hip/hip_runtime.h>
#include <hip/hip_fp16.h>
#include <math.h>
#include <type_traits>

typedef _Float16 half8 __attribute__((ext_vector_type(8)));
typedef float floatx4 __attribute__((ext_vector_type(4)));

#define RSHIFT 9          // rows per bucket = 512; NB = ceil(N/512) <= 256

// ---------------- K1: row-bucket histogram (LDS) + W convert ----------------
__global__ __launch_bounds__(256) void hist_conv_kernel(
        const int* __restrict__ row, int E, int* __restrict__ bucketsize,
        const float* __restrict__ W1, const float* __restrict__ W2,
        const float* __restrict__ W3, _Float16* __restrict__ Wt1,
        _Float16* __restrict__ Wt2, _Float16* __restrict__ Wt3, int histBlocks) {
    int tid = threadIdx.x;
    if ((int)blockIdx.x < histBlocks) {
        __shared__ int h[256];
        h[tid] = 0;
        __syncthreads();
        int base = blockIdx.x * 16384;
#pragma unroll
        for (int it = 0; it < 16; ++it) {
            int e0 = base + it * 1024 + tid * 4;
            if (e0 + 3 < E) {
                int4 r4 = *(const int4*)&row[e0];
                atomicAdd(&h[r4.x >> RSHIFT], 1);
                atomicAdd(&h[r4.y >> RSHIFT], 1);
                atomicAdd(&h[r4.z >> RSHIFT], 1);
                atomicAdd(&h[r4.w >> RSHIFT], 1);
            } else {
#pragma unroll
                for (int j = 0; j < 4; ++j)
                    if (e0 + j < E) atomicAdd(&h[row[e0 + j] >> RSHIFT], 1);
            }
        }
        __syncthreads();
        if (h[tid]) atomicAdd(&bucketsize[tid], h[tid]);
    } else {
        int g = ((int)blockIdx.x - histBlocks) * 256 + tid;
        if (g < 16384) {
            int k = g >> 7, n = g & 127;
            Wt1[n * 128 + k] = (_Float16)W1[g];
        } else if (g < 32768) {
            int h2 = g - 16384; int k = h2 >> 7, n = h2 & 127;
            Wt2[n * 128 + k] = (_Float16)W2[h2];
        } else if (g < 40960) {
            int h2 = g - 32768; int k = h2 >> 6, n = h2 & 63;
            Wt3[n * 128 + k] = (_Float16)W3[h2];
        }
    }
}

// inline exclusive-base scan of bucketsize into LDS (s_incl = inclusive sums)
__device__ __forceinline__ void scan_bucketsize(const int* __restrict__ bucketsize,
                                                int* s_incl, int* s_val) {
    int tid = threadIdx.x & 255;           // first 256 threads participate
    if (threadIdx.x < 256) {
        int v = bucketsize[tid];
        s_val[tid] = v;
        s_incl[tid] = v;
    }
    __syncthreads();
    for (int off = 1; off < 256; off <<= 1) {
        int v = 0;
        if (threadIdx.x < 256 && tid >= off) v = s_incl[tid - off];
        __syncthreads();
        if (threadIdx.x < 256) s_incl[tid] += v;
        __syncthreads();
    }
}

// ---------------- K2: radix partition by row-bucket (no weights, 4B entries) ----------------
__global__ __launch_bounds__(256) void partition_kernel(
        const int* __restrict__ row, const int* __restrict__ col,
        const int* __restrict__ bucketsize, int* __restrict__ gcur,
        int* __restrict__ emid, int E, int NB) {
    __shared__ int sincl[256], sval[256];
    __shared__ int scnt[256], sofs[256], gslot[256];
    __shared__ int sdata[4096];
    __shared__ unsigned short sbkt[4096];

    int tid = threadIdx.x;
    scan_bucketsize(bucketsize, sincl, sval);   // has trailing __syncthreads
    int mybase = sincl[tid] - sval[tid];        // bucketbase[tid]
    scnt[tid] = 0;
    __syncthreads();

    int base = blockIdx.x * 4096;
    int epk[16]; int eb[16]; int eidx[16];
#pragma unroll
    for (int v = 0; v < 4; ++v) {
        int e0 = base + v * 1024 + tid * 4;
        int4 r4, c4;
        bool full = (e0 + 3 < E);
        if (full) {
            r4 = *(const int4*)&row[e0];
            c4 = *(const int4*)&col[e0];
        }
#pragma unroll
        for (int j = 0; j < 4; ++j) {
            int u = v * 4 + j;
            eb[u] = -1;
            int r, c;
            if (full) {
                r = (&r4.x)[j]; c = (&c4.x)[j];
            } else {
                if (e0 + j >= E) continue;
                r = row[e0 + j]; c = col[e0 + j];
            }
            int b = r >> RSHIFT;
            eb[u] = b;
            eidx[u] = atomicAdd(&scnt[b], 1);
            epk[u] = c | ((r & ((1 << RSHIFT) - 1)) << 20);
        }
    }
    __syncthreads();
    sofs[tid] = scnt[tid];
    __syncthreads();
    for (int off = 1; off < 256; off <<= 1) {
        int v = (tid >= off) ? sofs[tid - off] : 0;
        __syncthreads();
        sofs[tid] += v;
        __syncthreads();
    }
    int excl = sofs[tid] - scnt[tid];
    sofs[tid] = excl;
    if (tid < NB && scnt[tid] > 0)
        gslot[tid] = mybase + atomicAdd(&gcur[tid], scnt[tid]);
    __syncthreads();
#pragma unroll
    for (int u = 0; u < 16; ++u) {
        if (eb[u] >= 0) {
            int idx = sofs[eb[u]] + eidx[u];
            sdata[idx] = epk[u];
            sbkt[idx] = (unsigned short)eb[u];
        }
    }
    __syncthreads();
    int cntR = min(4096, E - base);
    for (int i = tid; i < cntR; i += 256) {
        int b = sbkt[i];
        emid[gslot[b] + (i - sofs[b])] = sdata[i];
    }
}

// ---------------- GSO helpers ----------------
__device__ __forceinline__ float pow_z(float d, float e) {
    float p = powf(d, e);
    return isinf(p) ? 0.0f : p;   // reference zeroes inf from 0**negative
}

__device__ __forceinline__ void gso_coeff(float deg, const float* __restrict__ p1,
                                          const float* __restrict__ p2,
                                          float4* cf, float* ws) {
    float m1a = p1[0], m2a = p1[1], m3a = p1[2], e1a = p1[3], e2a = p1[4], e3a = p1[5], aa = p1[6];
    float m1b = p2[0], m2b = p2[1], m3b = p2[2], e1b = p2[3], e2b = p2[4], e3b = p2[5], ab = p2[6];
    float d1 = deg + aa, d2 = deg + ab;
    float pa1 = pow_z(d1, e1a), pa2 = pow_z(d1, e2a), pa3 = pow_z(d1, e3a);
    float pb1 = pow_z(d2, e1b), pb2 = pow_z(d2, e2b), pb3 = pow_z(d2, e3b);
    *cf = make_float4(m2a * pa2, pa3, m2b * pb2, pb3);
    *ws = m1a * pa1 + m2a * pa2 * pa3 + m3a
        + m1b * pb1 + m2b * pb2 * pb3 + m3b;
}

// ---------------- K3: per-bucket degree count + rowptr slice + GSO coeff ----------------
__global__ __launch_bounds__(256) void bucket_deg_kernel(
        const int* __restrict__ bucketsize, const int* __restrict__ emid,
        int* __restrict__ rowptr,
        const float* __restrict__ p1, const float* __restrict__ p2,
        float4* __restrict__ coeff, float* __restrict__ wself, int N, int NB) {
    __shared__ int sincl[256], sval[256];
    __shared__ int cnt[512];
    __shared__ int ssum[256];
    int b = blockIdx.x;
    int tid = threadIdx.x;
    scan_bucketsize(bucketsize, sincl, sval);
    int seg0 = sincl[b] - sval[b];
    int seg1 = sincl[b];
    int row0 = b << RSHIFT;
    int nrows = min(512, N - row0);
    cnt[tid] = 0; cnt[tid + 256] = 0;
    __syncthreads();
    for (int i = seg0 + tid; i < seg1; i += 256)
        atomicAdd(&cnt[((unsigned)emid[i]) >> 20], 1);
    __syncthreads();
    int a0 = cnt[2 * tid], a1 = cnt[2 * tid + 1];
    int tsum = a0 + a1;
    ssum[tid] = tsum;
    __syncthreads();
    for (int off = 1; off < 256; off <<= 1) {
        int v = (tid >= off) ? ssum[tid - off] : 0;
        __syncthreads();
        ssum[tid] += v;
        __syncthreads();
    }
    int excl = ssum[tid] - tsum;
    if (2 * tid < nrows) {
        rowptr[row0 + 2 * tid] = seg0 + excl;
        float4 cf; float ws;
        gso_coeff((float)a0, p1, p2, &cf, &ws);
        coeff[row0 + 2 * tid] = cf;
        wself[row0 + 2 * tid] = ws;
    }
    if (2 * tid + 1 < nrows) {
        rowptr[row0 + 2 * tid + 1] = seg0 + excl + a0;
        float4 cf; float ws;
        gso_coeff((float)a1, p1, p2, &cf, &ws);
        coeff[row0 + 2 * tid + 1] = cf;
        wself[row0 + 2 * tid + 1] = ws;
    }
    if (tid == 0 && b == NB - 1) rowptr[N] = seg1;
}

// ---------------- K4: per-bucket weight compute + final CSR placement ----------------
__global__ __launch_bounds__(256) void bucket_place_kernel(
        const int* __restrict__ bucketsize, const int* __restrict__ emid,
        const int* __restrict__ rowptr, const float4* __restrict__ coeff,
        int2* __restrict__ epack, int N) {
    __shared__ int sincl[256], sval[256];
    __shared__ int lcur[512];
    __shared__ float4 scoef[512];
    int b = blockIdx.x;
    int tid = threadIdx.x;
    scan_bucketsize(bucketsize, sincl, sval);
    int seg0 = sincl[b] - sval[b];
    int seg1 = sincl[b];
    int row0 = b << RSHIFT;
    int nrows = min(512, N - row0);
#pragma unroll
    for (int u = 0; u < 2; ++u) {
        int j = tid + u * 256;
        if (j < nrows) {
            lcur[j] = rowptr[row0 + j];
            scoef[j] = coeff[row0 + j];
        }
    }
    __syncthreads();
    for (int i = seg0 + tid; i < seg1; i += 256) {
        int v = emid[i];
        int rl = ((unsigned)v) >> 20;
        int c = v & 0xFFFFF;
        float4 cr = scoef[rl];
        float4 cc = coeff[c];
        float w = cr.x * cc.y + cr.z * cc.w;
        int pos = atomicAdd(&lcur[rl], 1);
        epack[pos] = make_int2(c, __float_as_int(w));
    }
}

// ---------------- MFMA GEMM: A[n x 128] @ Wt[TN x 128] -> C[n x TN] fp16 ----------------
template<int TN, typename AT>
__global__ __launch_bounds__(256) void gemm_mfma(const AT* __restrict__ A,
        const _Float16* __restrict__ Wt, _Float16* __restrict__ C, int n) {
    constexpr int K = 128;
    constexpr int TM = 128;
    constexpr int LDK = K + 8;
    __shared__ _Float16 As[TM][LDK];
    __shared__ _Float16 Bs[TN][LDK];

    int tid = threadIdx.x;
    int wave = tid >> 6, lane = tid & 63;
    int q = lane >> 4, t = lane & 15;
    int rowbase = blockIdx.x * TM;

    if constexpr (std::is_same<AT, float>::value) {
        for (int i = tid; i < TM * K / 4; i += 256) {
            int r = i >> 5;
            int kc = (i & 31) * 4;
            int rr = rowbase + r;
            float4 v = make_float4(0.f, 0.f, 0.f, 0.f);
            if (rr < n) v = *(const float4*)&A[(size_t)rr * K + kc];
            As[r][kc + 0] = (_Float16)v.x;
            As[r][kc + 1] = (_Float16)v.y;
            As[r][kc + 2] = (_Float16)v.z;
            As[r][kc + 3] = (_Float16)v.w;
        }
    } else {
        for (int i = tid; i < TM * K / 8; i += 256) {
            int r = i >> 4;
            int kc = (i & 15) * 8;
            int rr = rowbase + r;
            uint4 v = make_uint4(0u, 0u, 0u, 0u);
            if (rr < n) v = *(const uint4*)&A[(size_t)rr * K + kc];
            *(uint4*)&As[r][kc] = v;
        }
    }
    for (int i = tid; i < TN * K / 8; i += 256) {
        int nr = i >> 4;
        int kc = (i & 15) * 8;
        *(uint4*)&Bs[nr][kc] = *(const uint4*)&Wt[(size_t)nr * K + kc];
    }
    __syncthreads();

    int m0 = wave * 32;
    floatx4 acc0[TN / 16], acc1[TN / 16];
#pragma unroll
    for (int nt = 0; nt < TN / 16; ++nt) {
        acc0[nt] = (floatx4){0.f, 0.f, 0.f, 0.f};
        acc1[nt] = (floatx4){0.f, 0.f, 0.f, 0.f};
    }

#pragma unroll
    for (int kk = 0; kk < K; kk += 32) {
        half8 a0 = *(const half8*)&As[m0 + t][kk + q * 8];
        half8 a1 = *(const half8*)&As[m0 + 16 + t][kk + q * 8];
#pragma unroll
        for (int nt = 0; nt < TN / 16; ++nt) {
            half8 b = *(const half8*)&Bs[nt * 16 + t][kk + q * 8];
            acc0[nt] = __builtin_amdgcn_mfma_f32_16x16x32_f16(a0, b, acc0[nt], 0, 0, 0);
            acc1[nt] = __builtin_amdgcn_mfma_f32_16x16x32_f16(a1, b, acc1[nt], 0, 0, 0);
        }
    }

#pragma unroll
    for (int nt = 0; nt < TN / 16; ++nt) {
#pragma unroll
        for (int r = 0; r < 4; ++r) {
            int rr0 = rowbase + m0 + q * 4 + r;
            if (rr0 < n) C[(size_t)rr0 * TN + nt * 16 + t] = (_Float16)acc0[nt][r];
            int rr1 = rr0 + 16;
            if (rr1 < n) C[(size_t)rr1 * TN + nt * 16 + t] = (_Float16)acc1[nt][r];
        }
    }
}

// ---------------- CSR aggregation, D=128, fp16 in/out, relu ----------------
// One-shot: 1024-thread blocks, 16 nodes/block, one node per wave (R10 form,
// 4x fewer workgroups). 16/8/4/1 unpredicated cascade.
__global__ __launch_bounds__(1024) void agg128_kernel(const __half2* __restrict__ H,
        const int* __restrict__ rowptr, const int2* __restrict__ epack,
        const float* __restrict__ wself, const float* __restrict__ bias,
        __half2* __restrict__ out, int n) {
    int node = blockIdx.x * 16 + (threadIdx.x >> 6);
    if (node >= n) return;
    int lane = threadIdx.x & 63;
    int start = rowptr[node], end = rowptr[node + 1];
    float ws = wself[node];
    float2 hs = __half22float2(H[(size_t)node * 64 + lane]);
    float ax = ws * hs.x, ay = ws * hs.y;
    int e = start;
    for (; e + 16 <= end; e += 16) {
        int2 p[16];
#pragma unroll
        for (int j = 0; j < 16; ++j) p[j] = epack[e + j];
        __half2 hh[16];
#pragma unroll
        for (int j = 0; j < 16; ++j) hh[j] = H[(size_t)p[j].x * 64 + lane];
#pragma unroll
        for (int j = 0; j < 16; ++j) {
            float w = __int_as_float(p[j].y);
            float2 f = __half22float2(hh[j]);
            ax += w * f.x; ay += w * f.y;
        }
    }
    if (e + 8 <= end) {
        int2 p[8];
#pragma unroll
        for (int j = 0; j < 8; ++j) p[j] = epack[e + j];
        __half2 hh[8];
#pragma unroll
        for (int j = 0; j < 8; ++j) hh[j] = H[(size_t)p[j].x * 64 + lane];
#pragma unroll
        for (int j = 0; j < 8; ++j) {
            float w = __int_as_float(p[j].y);
            float2 f = __half22float2(hh[j]);
            ax += w * f.x; ay += w * f.y;
        }
        e += 8;
    }
    if (e + 4 <= end) {
        int2 p[4];
#pragma unroll
        for (int j = 0; j < 4; ++j) p[j] = epack[e + j];
        __half2 hh[4];
#pragma unroll
        for (int j = 0; j < 4; ++j) hh[j] = H[(size_t)p[j].x * 64 + lane];
#pragma unroll
        for (int j = 0; j < 4; ++j) {
            float w = __int_as_float(p[j].y);
            float2 f = __half22float2(hh[j]);
            ax += w * f.x; ay += w * f.y;
        }
        e += 4;
    }
    for (; e < end; ++e) {
        int2 pe = epack[e];
        float w = __int_as_float(pe.y);
        float2 f = __half22float2(H[(size_t)pe.x * 64 + lane]);
        ax += w * f.x; ay += w * f.y;
    }
    float2 b = *(const float2*)&bias[2 * lane];
    float vx = fmaxf(ax + b.x, 0.0f);
    float vy = fmaxf(ay + b.y, 0.0f);
    out[(size_t)node * 64 + lane] = __floats2half2_rn(vx, vy);
}

// ---------------- CSR aggregation, D=64, fp16 in / fp32 out, no relu ----------------
__global__ __launch_bounds__(1024) void agg64_kernel(const __half* __restrict__ H,
        const int* __restrict__ rowptr, const int2* __restrict__ epack,
        const float* __restrict__ wself, const float* __restrict__ bias,
        float* __restrict__ out, int n) {
    int node = blockIdx.x * 16 + (threadIdx.x >> 6);
    if (node >= n) return;
    int lane = threadIdx.x & 63;
    int start = rowptr[node], end = rowptr[node + 1];
    float ws = wself[node];
    float acc = ws * __half2float(H[(size_t)node * 64 + lane]);
    int e = start;
    for (; e + 16 <= end; e += 16) {
        int2 p[16];
#pragma unroll
        for (int j = 0; j < 16; ++j) p[j] = epack[e + j];
        float f[16];
#pragma unroll
        for (int j = 0; j < 16; ++j) f[j] = __half2float(H[(size_t)p[j].x * 64 + lane]);
#pragma unroll
        for (int j = 0; j < 16; ++j) acc += __int_as_float(p[j].y) * f[j];
    }
    if (e + 8 <= end) {
        int2 p[8];
#pragma unroll
        for (int j = 0; j < 8; ++j) p[j] = epack[e + j];
        float f[8];
#pragma unroll
        for (int j = 0; j < 8; ++j) f[j] = __half2float(H[(size_t)p[j].x * 64 + lane]);
#pragma unroll
        for (int j = 0; j < 8; ++j) acc += __int_as_float(p[j].y) * f[j];
        e += 8;
    }
    if (e + 4 <= end) {
        int2 p[4];
#pragma unroll
        for (int j = 0; j < 4; ++j) p[j] = epack[e + j];
        float f[4];
#pragma unroll
        for (int j = 0; j < 4; ++j) f[j] = __half2float(H[(size_t)p[j].x * 64 + lane]);
#pragma unroll
        for (int j = 0; j < 4; ++j) acc += __int_as_float(p[j].y) * f[j];
        e += 4;
    }
    for (; e < end; ++e) {
        int2 pe = epack[e];
        acc += __int_as_float(pe.y) * __half2float(H[(size_t)pe.x * 64 + lane]);
    }
    out[(size_t)node * 64 + lane] = acc + bias[lane];
}

// ---------------- launch ----------------
extern "C" void kernel_launch(void* const* d_in, const int* in_sizes, int n_in,
                              void* d_out, int out_size, void* d_ws, size_t ws_size,
                              hipStream_t stream) {
    const float* x  = (const float*)d_in[0];
    const int*   ei = (const int*)d_in[1];
    const float* W1 = (const float*)d_in[2];
    const float* b1 = (const float*)d_in[3];
    const float* W2 = (const float*)d_in[4];
    const float* b2 = (const float*)d_in[5];
    const float* W3 = (const float*)d_in[6];
    const float* b3 = (const float*)d_in[7];
    const float* p1 = (const float*)d_in[8];
    const float* p2 = (const float*)d_in[9];

    const int N = in_sizes[0] / 128;
    const int E = in_sizes[1] / 2;
    const int* row = ei;
    const int* col = ei + E;
    const int NB = ((N - 1) >> RSHIFT) + 1;      // 196 buckets for N=100000

    char* p = (char*)d_ws;
    auto alloc = [&](size_t bytes) -> void* {
        void* q = (void*)p;
        p += (bytes + 255) & ~(size_t)255;
        return q;
    };
    int*      bucketsize = (int*)alloc(256 * 4);
    int*      gcur       = (int*)alloc(256 * 4);         // contiguous with bucketsize: one memset
    int*      rowptr     = (int*)alloc((size_t)(N + 1) * 4);
    float4*   coeff      = (float4*)alloc((size_t)N * 16);
    float*    wself      = (float*)alloc((size_t)N * 4);
    int*      emid       = (int*)alloc((size_t)E * 4);
    int2*     epack      = (int2*)alloc((size_t)E * 8);
    _Float16* Wt1        = (_Float16*)alloc(128 * 128 * 2);
    _Float16* Wt2        = (_Float16*)alloc(128 * 128 * 2);
    _Float16* Wt3        = (_Float16*)alloc(128 * 64 * 2);
    _Float16* bufH       = (_Float16*)alloc((size_t)N * 128 * 2);
    _Float16* actH       = (_Float16*)alloc((size_t)N * 128 * 2);
    (void)ws_size; (void)n_in;

    hipMemsetAsync(bucketsize, 0, 512 * 4, stream);      // bucketsize + gcur

    const int histBlocks = (E + 16383) / 16384;          // 98
    const int convBlocks = (40960 + 255) / 256;          // 160
    hist_conv_kernel<<<histBlocks + convBlocks, 256, 0, stream>>>(
        row, E, bucketsize, W1, W2, W3, Wt1, Wt2, Wt3, histBlocks);
    partition_kernel<<<(E + 4095) / 4096, 256, 0, stream>>>(row, col, bucketsize, gcur,
                                                            emid, E, NB);
    bucket_deg_kernel<<<NB, 256, 0, stream>>>(bucketsize, emid, rowptr, p1, p2,
                                              coeff, wself, N, NB);
    bucket_place_kernel<<<NB, 256, 0, stream>>>(bucketsize, emid, rowptr, coeff, epack, N);

    float* out = (float*)d_out;
    int gemmGrid = (N + 127) / 128;
    int aggGrid = (N + 15) / 16;
    // layer 1
    gemm_mfma<128, float><<<gemmGrid, 256, 0, stream>>>(x, Wt1, bufH, N);
    agg128_kernel<<<aggGrid, 1024, 0, stream>>>((const __half2*)bufH, rowptr, epack, wself,
                                                b1, (__half2*)actH, N);
    // layer 2
    gemm_mfma<128, _Float16><<<gemmGrid, 256, 0, stream>>>(actH, Wt2, bufH, N);
    agg128_kernel<<<aggGrid, 1024, 0, stream>>>((const __half2*)bufH, rowptr, epack, wself,
                                                b2, (__half2*)actH, N);
    // layer 3 (D_OUT=64, no relu)
    gemm_mfma<64, _Float16><<<gemmGrid, 256, 0, stream>>>(actH, Wt3, bufH, N);
    agg64_kernel<<<aggGrid, 1024, 0, stream>>>((const __half*)bufH, rowptr, epack, wself,
                                               b3, out, N);
}

// Round 13
// 422.063 us; speedup vs baseline: 1.1754x; 1.1754x over previous
//
#include <hip/hip_runtime.h>
#include <hip/hip_fp16.h>
#include <math.h>
#include <type_traits>

typedef _Float16 half8 __attribute__((ext_vector_type(8)));
typedef float floatx4 __attribute__((ext_vector_type(4)));

#define RSHIFT 9          // rows per bucket = 512; NB = ceil(N/512) <= 256

// ---------------- K1: row-bucket histogram (LDS) + W convert ----------------
__global__ __launch_bounds__(256) void hist_conv_kernel(
        const int* __restrict__ row, int E, int* __restrict__ bucketsize,
        const float* __restrict__ W1, const float* __restrict__ W2,
        const float* __restrict__ W3, _Float16* __restrict__ Wt1,
        _Float16* __restrict__ Wt2, _Float16* __restrict__ Wt3, int histBlocks) {
    int tid = threadIdx.x;
    if ((int)blockIdx.x < histBlocks) {
        __shared__ int h[256];
        h[tid] = 0;
        __syncthreads();
        int base = blockIdx.x * 16384;
#pragma unroll
        for (int it = 0; it < 16; ++it) {
            int e0 = base + it * 1024 + tid * 4;
            if (e0 + 3 < E) {
                int4 r4 = *(const int4*)&row[e0];
                atomicAdd(&h[r4.x >> RSHIFT], 1);
                atomicAdd(&h[r4.y >> RSHIFT], 1);
                atomicAdd(&h[r4.z >> RSHIFT], 1);
                atomicAdd(&h[r4.w >> RSHIFT], 1);
            } else {
#pragma unroll
                for (int j = 0; j < 4; ++j)
                    if (e0 + j < E) atomicAdd(&h[row[e0 + j] >> RSHIFT], 1);
            }
        }
        __syncthreads();
        if (h[tid]) atomicAdd(&bucketsize[tid], h[tid]);
    } else {
        int g = ((int)blockIdx.x - histBlocks) * 256 + tid;
        if (g < 16384) {
            int k = g >> 7, n = g & 127;
            Wt1[n * 128 + k] = (_Float16)W1[g];
        } else if (g < 32768) {
            int h2 = g - 16384; int k = h2 >> 7, n = h2 & 127;
            Wt2[n * 128 + k] = (_Float16)W2[h2];
        } else if (g < 40960) {
            int h2 = g - 32768; int k = h2 >> 6, n = h2 & 63;
            Wt3[n * 128 + k] = (_Float16)W3[h2];
        }
    }
}

// inline exclusive-base scan of bucketsize into LDS (s_incl = inclusive sums)
__device__ __forceinline__ void scan_bucketsize(const int* __restrict__ bucketsize,
                                                int* s_incl, int* s_val) {
    int tid = threadIdx.x & 255;
    if (threadIdx.x < 256) {
        int v = bucketsize[tid];
        s_val[tid] = v;
        s_incl[tid] = v;
    }
    __syncthreads();
    for (int off = 1; off < 256; off <<= 1) {
        int v = 0;
        if (threadIdx.x < 256 && tid >= off) v = s_incl[tid - off];
        __syncthreads();
        if (threadIdx.x < 256) s_incl[tid] += v;
        __syncthreads();
    }
}

// ---------------- K2: radix partition by row-bucket (8192 edges/block) ----------------
__global__ __launch_bounds__(256) void partition_kernel(
        const int* __restrict__ row, const int* __restrict__ col,
        const int* __restrict__ bucketsize, int* __restrict__ gcur,
        int* __restrict__ emid, int E, int NB) {
    __shared__ int sincl[256], sval[256];
    __shared__ int scnt[256], sofs[256], gslot[256];
    __shared__ int sdata[8192];
    __shared__ unsigned short sbkt[8192];

    int tid = threadIdx.x;
    scan_bucketsize(bucketsize, sincl, sval);   // trailing __syncthreads
    int mybase = sincl[tid] - sval[tid];        // bucketbase[tid]
    scnt[tid] = 0;
    __syncthreads();

    int base = blockIdx.x * 8192;
    int epk[32]; int eb[32]; int eidx[32];
#pragma unroll
    for (int v = 0; v < 8; ++v) {
        int e0 = base + v * 1024 + tid * 4;
        int4 r4, c4;
        bool full = (e0 + 3 < E);
        if (full) {
            r4 = *(const int4*)&row[e0];
            c4 = *(const int4*)&col[e0];
        }
#pragma unroll
        for (int j = 0; j < 4; ++j) {
            int u = v * 4 + j;
            eb[u] = -1;
            int r, c;
            if (full) {
                r = (&r4.x)[j]; c = (&c4.x)[j];
            } else {
                if (e0 + j >= E) continue;
                r = row[e0 + j]; c = col[e0 + j];
            }
            int b = r >> RSHIFT;
            eb[u] = b;
            eidx[u] = atomicAdd(&scnt[b], 1);
            epk[u] = c | ((r & ((1 << RSHIFT) - 1)) << 20);
        }
    }
    __syncthreads();
    sofs[tid] = scnt[tid];
    __syncthreads();
    for (int off = 1; off < 256; off <<= 1) {
        int v = (tid >= off) ? sofs[tid - off] : 0;
        __syncthreads();
        sofs[tid] += v;
        __syncthreads();
    }
    int excl = sofs[tid] - scnt[tid];
    sofs[tid] = excl;
    if (tid < NB && scnt[tid] > 0)
        gslot[tid] = mybase + atomicAdd(&gcur[tid], scnt[tid]);
    __syncthreads();
#pragma unroll
    for (int u = 0; u < 32; ++u) {
        if (eb[u] >= 0) {
            int idx = sofs[eb[u]] + eidx[u];
            sdata[idx] = epk[u];
            sbkt[idx] = (unsigned short)eb[u];
        }
    }
    __syncthreads();
    int cntR = min(8192, E - base);
    for (int i = tid; i < cntR; i += 256) {
        int b = sbkt[i];
        emid[gslot[b] + (i - sofs[b])] = sdata[i];
    }
}

// ---------------- GSO helpers ----------------
__device__ __forceinline__ float pow_z(float d, float e) {
    float p = powf(d, e);
    return isinf(p) ? 0.0f : p;   // reference zeroes inf from 0**negative
}

__device__ __forceinline__ void gso_coeff(float deg, const float* __restrict__ p1,
                                          const float* __restrict__ p2,
                                          float4* cf, float* ws) {
    float m1a = p1[0], m2a = p1[1], m3a = p1[2], e1a = p1[3], e2a = p1[4], e3a = p1[5], aa = p1[6];
    float m1b = p2[0], m2b = p2[1], m3b = p2[2], e1b = p2[3], e2b = p2[4], e3b = p2[5], ab = p2[6];
    float d1 = deg + aa, d2 = deg + ab;
    float pa1 = pow_z(d1, e1a), pa2 = pow_z(d1, e2a), pa3 = pow_z(d1, e3a);
    float pb1 = pow_z(d2, e1b), pb2 = pow_z(d2, e2b), pb3 = pow_z(d2, e3b);
    *cf = make_float4(m2a * pa2, pa3, m2b * pb2, pb3);
    *ws = m1a * pa1 + m2a * pa2 * pa3 + m3a
        + m1b * pb1 + m2b * pb2 * pb3 + m3b;
}

// ---------------- K3: per-bucket degree count + rowptr slice + GSO coeff ----------------
__global__ __launch_bounds__(256) void bucket_deg_kernel(
        const int* __restrict__ bucketsize, const int* __restrict__ emid,
        int* __restrict__ rowptr,
        const float* __restrict__ p1, const float* __restrict__ p2,
        float4* __restrict__ coeff, float* __restrict__ wself, int N, int NB) {
    __shared__ int sincl[256], sval[256];
    __shared__ int cnt[512];
    __shared__ int ssum[256];
    int b = blockIdx.x;
    int tid = threadIdx.x;
    scan_bucketsize(bucketsize, sincl, sval);
    int seg0 = sincl[b] - sval[b];
    int seg1 = sincl[b];
    int row0 = b << RSHIFT;
    int nrows = min(512, N - row0);
    cnt[tid] = 0; cnt[tid + 256] = 0;
    __syncthreads();
    for (int i = seg0 + tid; i < seg1; i += 256)
        atomicAdd(&cnt[((unsigned)emid[i]) >> 20], 1);
    __syncthreads();
    int a0 = cnt[2 * tid], a1 = cnt[2 * tid + 1];
    int tsum = a0 + a1;
    ssum[tid] = tsum;
    __syncthreads();
    for (int off = 1; off < 256; off <<= 1) {
        int v = (tid >= off) ? ssum[tid - off] : 0;
        __syncthreads();
        ssum[tid] += v;
        __syncthreads();
    }
    int excl = ssum[tid] - tsum;
    if (2 * tid < nrows) {
        rowptr[row0 + 2 * tid] = seg0 + excl;
        float4 cf; float ws;
        gso_coeff((float)a0, p1, p2, &cf, &ws);
        coeff[row0 + 2 * tid] = cf;
        wself[row0 + 2 * tid] = ws;
    }
    if (2 * tid + 1 < nrows) {
        rowptr[row0 + 2 * tid + 1] = seg0 + excl + a0;
        float4 cf; float ws;
        gso_coeff((float)a1, p1, p2, &cf, &ws);
        coeff[row0 + 2 * tid + 1] = cf;
        wself[row0 + 2 * tid + 1] = ws;
    }
    if (tid == 0 && b == NB - 1) rowptr[N] = seg1;
}

// ---------------- K4: per-bucket weight compute + final CSR placement ----------------
__global__ __launch_bounds__(256) void bucket_place_kernel(
        const int* __restrict__ bucketsize, const int* __restrict__ emid,
        const int* __restrict__ rowptr, const float4* __restrict__ coeff,
        int2* __restrict__ epack, int N) {
    __shared__ int sincl[256], sval[256];
    __shared__ int lcur[512];
    __shared__ float4 scoef[512];
    int b = blockIdx.x;
    int tid = threadIdx.x;
    scan_bucketsize(bucketsize, sincl, sval);
    int seg0 = sincl[b] - sval[b];
    int seg1 = sincl[b];
    int row0 = b << RSHIFT;
    int nrows = min(512, N - row0);
#pragma unroll
    for (int u = 0; u < 2; ++u) {
        int j = tid + u * 256;
        if (j < nrows) {
            lcur[j] = rowptr[row0 + j];
            scoef[j] = coeff[row0 + j];
        }
    }
    __syncthreads();
    for (int i = seg0 + tid; i < seg1; i += 256) {
        int v = emid[i];
        int rl = ((unsigned)v) >> 20;
        int c = v & 0xFFFFF;
        float4 cr = scoef[rl];
        float4 cc = coeff[c];
        float w = cr.x * cc.y + cr.z * cc.w;
        int pos = atomicAdd(&lcur[rl], 1);
        epack[pos] = make_int2(c, __float_as_int(w));
    }
}

// ---------------- MFMA GEMM: A[n x 128] @ Wt[TN x 128] -> C[n x TN] fp16 ----------------
template<int TN, typename AT>
__global__ __launch_bounds__(256) void gemm_mfma(const AT* __restrict__ A,
        const _Float16* __restrict__ Wt, _Float16* __restrict__ C, int n) {
    constexpr int K = 128;
    constexpr int TM = 128;
    constexpr int LDK = K + 8;
    __shared__ _Float16 As[TM][LDK];
    __shared__ _Float16 Bs[TN][LDK];

    int tid = threadIdx.x;
    int wave = tid >> 6, lane = tid & 63;
    int q = lane >> 4, t = lane & 15;
    int rowbase = blockIdx.x * TM;

    if constexpr (std::is_same<AT, float>::value) {
        for (int i = tid; i < TM * K / 4; i += 256) {
            int r = i >> 5;
            int kc = (i & 31) * 4;
            int rr = rowbase + r;
            float4 v = make_float4(0.f, 0.f, 0.f, 0.f);
            if (rr < n) v = *(const float4*)&A[(size_t)rr * K + kc];
            As[r][kc + 0] = (_Float16)v.x;
            As[r][kc + 1] = (_Float16)v.y;
            As[r][kc + 2] = (_Float16)v.z;
            As[r][kc + 3] = (_Float16)v.w;
        }
    } else {
        for (int i = tid; i < TM * K / 8; i += 256) {
            int r = i >> 4;
            int kc = (i & 15) * 8;
            int rr = rowbase + r;
            uint4 v = make_uint4(0u, 0u, 0u, 0u);
            if (rr < n) v = *(const uint4*)&A[(size_t)rr * K + kc];
            *(uint4*)&As[r][kc] = v;
        }
    }
    for (int i = tid; i < TN * K / 8; i += 256) {
        int nr = i >> 4;
        int kc = (i & 15) * 8;
        *(uint4*)&Bs[nr][kc] = *(const uint4*)&Wt[(size_t)nr * K + kc];
    }
    __syncthreads();

    int m0 = wave * 32;
    floatx4 acc0[TN / 16], acc1[TN / 16];
#pragma unroll
    for (int nt = 0; nt < TN / 16; ++nt) {
        acc0[nt] = (floatx4){0.f, 0.f, 0.f, 0.f};
        acc1[nt] = (floatx4){0.f, 0.f, 0.f, 0.f};
    }

#pragma unroll
    for (int kk = 0; kk < K; kk += 32) {
        half8 a0 = *(const half8*)&As[m0 + t][kk + q * 8];
        half8 a1 = *(const half8*)&As[m0 + 16 + t][kk + q * 8];
#pragma unroll
        for (int nt = 0; nt < TN / 16; ++nt) {
            half8 b = *(const half8*)&Bs[nt * 16 + t][kk + q * 8];
            acc0[nt] = __builtin_amdgcn_mfma_f32_16x16x32_f16(a0, b, acc0[nt], 0, 0, 0);
            acc1[nt] = __builtin_amdgcn_mfma_f32_16x16x32_f16(a1, b, acc1[nt], 0, 0, 0);
        }
    }

#pragma unroll
    for (int nt = 0; nt < TN / 16; ++nt) {
#pragma unroll
        for (int r = 0; r < 4; ++r) {
            int rr0 = rowbase + m0 + q * 4 + r;
            if (rr0 < n) C[(size_t)rr0 * TN + nt * 16 + t] = (_Float16)acc0[nt][r];
            int rr1 = rr0 + 16;
            if (rr1 < n) C[(size_t)rr1 * TN + nt * 16 + t] = (_Float16)acc1[nt][r];
        }
    }
}

// ---------------- CSR aggregation, D=128, fp16 in/out, relu (R10 geometry) ----------------
__global__ __launch_bounds__(256) void agg128_kernel(const __half2* __restrict__ H,
        const int* __restrict__ rowptr, const int2* __restrict__ epack,
        const float* __restrict__ wself, const float* __restrict__ bias,
        __half2* __restrict__ out, int n) {
    int node = blockIdx.x * 4 + (threadIdx.x >> 6);
    if (node >= n) return;
    int lane = threadIdx.x & 63;
    int start = rowptr[node], end = rowptr[node + 1];
    float ws = wself[node];
    float2 hs = __half22float2(H[(size_t)node * 64 + lane]);
    float ax = ws * hs.x, ay = ws * hs.y;
    int e = start;
    for (; e + 16 <= end; e += 16) {
        int2 p[16];
#pragma unroll
        for (int j = 0; j < 16; ++j) p[j] = epack[e + j];
        __half2 hh[16];
#pragma unroll
        for (int j = 0; j < 16; ++j) hh[j] = H[(size_t)p[j].x * 64 + lane];
#pragma unroll
        for (int j = 0; j < 16; ++j) {
            float w = __int_as_float(p[j].y);
            float2 f = __half22float2(hh[j]);
            ax += w * f.x; ay += w * f.y;
        }
    }
    if (e + 8 <= end) {
        int2 p[8];
#pragma unroll
        for (int j = 0; j < 8; ++j) p[j] = epack[e + j];
        __half2 hh[8];
#pragma unroll
        for (int j = 0; j < 8; ++j) hh[j] = H[(size_t)p[j].x * 64 + lane];
#pragma unroll
        for (int j = 0; j < 8; ++j) {
            float w = __int_as_float(p[j].y);
            float2 f = __half22float2(hh[j]);
            ax += w * f.x; ay += w * f.y;
        }
        e += 8;
    }
    if (e + 4 <= end) {
        int2 p[4];
#pragma unroll
        for (int j = 0; j < 4; ++j) p[j] = epack[e + j];
        __half2 hh[4];
#pragma unroll
        for (int j = 0; j < 4; ++j) hh[j] = H[(size_t)p[j].x * 64 + lane];
#pragma unroll
        for (int j = 0; j < 4; ++j) {
            float w = __int_as_float(p[j].y);
            float2 f = __half22float2(hh[j]);
            ax += w * f.x; ay += w * f.y;
        }
        e += 4;
    }
    for (; e < end; ++e) {
        int2 pe = epack[e];
        float w = __int_as_float(pe.y);
        float2 f = __half22float2(H[(size_t)pe.x * 64 + lane]);
        ax += w * f.x; ay += w * f.y;
    }
    float2 b = *(const float2*)&bias[2 * lane];
    float vx = fmaxf(ax + b.x, 0.0f);
    float vy = fmaxf(ay + b.y, 0.0f);
    out[(size_t)node * 64 + lane] = __floats2half2_rn(vx, vy);
}

// ---------------- CSR aggregation, D=64, fp16 in / fp32 out, no relu ----------------
__global__ __launch_bounds__(256) void agg64_kernel(const __half* __restrict__ H,
        const int* __restrict__ rowptr, const int2* __restrict__ epack,
        const float* __restrict__ wself, const float* __restrict__ bias,
        float* __restrict__ out, int n) {
    int node = blockIdx.x * 4 + (threadIdx.x >> 6);
    if (node >= n) return;
    int lane = threadIdx.x & 63;
    int start = rowptr[node], end = rowptr[node + 1];
    float ws = wself[node];
    float acc = ws * __half2float(H[(size_t)node * 64 + lane]);
    int e = start;
    for (; e + 16 <= end; e += 16) {
        int2 p[16];
#pragma unroll
        for (int j = 0; j < 16; ++j) p[j] = epack[e + j];
        float f[16];
#pragma unroll
        for (int j = 0; j < 16; ++j) f[j] = __half2float(H[(size_t)p[j].x * 64 + lane]);
#pragma unroll
        for (int j = 0; j < 16; ++j) acc += __int_as_float(p[j].y) * f[j];
    }
    if (e + 8 <= end) {
        int2 p[8];
#pragma unroll
        for (int j = 0; j < 8; ++j) p[j] = epack[e + j];
        float f[8];
#pragma unroll
        for (int j = 0; j < 8; ++j) f[j] = __half2float(H[(size_t)p[j].x * 64 + lane]);
#pragma unroll
        for (int j = 0; j < 8; ++j) acc += __int_as_float(p[j].y) * f[j];
        e += 8;
    }
    if (e + 4 <= end) {
        int2 p[4];
#pragma unroll
        for (int j = 0; j < 4; ++j) p[j] = epack[e + j];
        float f[4];
#pragma unroll
        for (int j = 0; j < 4; ++j) f[j] = __half2float(H[(size_t)p[j].x * 64 + lane]);
#pragma unroll
        for (int j = 0; j < 4; ++j) acc += __int_as_float(p[j].y) * f[j];
        e += 4;
    }
    for (; e < end; ++e) {
        int2 pe = epack[e];
        acc += __int_as_float(pe.y) * __half2float(H[(size_t)pe.x * 64 + lane]);
    }
    out[(size_t)node * 64 + lane] = acc + bias[lane];
}

// ---------------- launch ----------------
extern "C" void kernel_launch(void* const* d_in, const int* in_sizes, int n_in,
                              void* d_out, int out_size, void* d_ws, size_t ws_size,
                              hipStream_t stream) {
    const float* x  = (const float*)d_in[0];
    const int*   ei = (const int*)d_in[1];
    const float* W1 = (const float*)d_in[2];
    const float* b1 = (const float*)d_in[3];
    const float* W2 = (const float*)d_in[4];
    const float* b2 = (const float*)d_in[5];
    const float* W3 = (const float*)d_in[6];
    const float* b3 = (const float*)d_in[7];
    const float* p1 = (const float*)d_in[8];
    const float* p2 = (const float*)d_in[9];

    const int N = in_sizes[0] / 128;
    const int E = in_sizes[1] / 2;
    const int* row = ei;
    const int* col = ei + E;
    const int NB = ((N - 1) >> RSHIFT) + 1;      // 196 buckets for N=100000

    char* p = (char*)d_ws;
    auto alloc = [&](size_t bytes) -> void* {
        void* q = (void*)p;
        p += (bytes + 255) & ~(size_t)255;
        return q;
    };
    int*      bucketsize = (int*)alloc(256 * 4);
    int*      gcur       = (int*)alloc(256 * 4);         // contiguous with bucketsize: one memset
    int*      rowptr     = (int*)alloc((size_t)(N + 1) * 4);
    float4*   coeff      = (float4*)alloc((size_t)N * 16);
    float*    wself      = (float*)alloc((size_t)N * 4);
    int*      emid       = (int*)alloc((size_t)E * 4);
    int2*     epack      = (int2*)alloc((size_t)E * 8);
    _Float16* Wt1        = (_Float16*)alloc(128 * 128 * 2);
    _Float16* Wt2        = (_Float16*)alloc(128 * 128 * 2);
    _Float16* Wt3        = (_Float16*)alloc(128 * 64 * 2);
    _Float16* bufH       = (_Float16*)alloc((size_t)N * 128 * 2);
    _Float16* actH       = (_Float16*)alloc((size_t)N * 128 * 2);
    (void)ws_size; (void)n_in;

    hipMemsetAsync(bucketsize, 0, 512 * 4, stream);      // bucketsize + gcur

    const int histBlocks = (E + 16383) / 16384;          // 98
    const int convBlocks = (40960 + 255) / 256;          // 160
    hist_conv_kernel<<<histBlocks + convBlocks, 256, 0, stream>>>(
        row, E, bucketsize, W1, W2, W3, Wt1, Wt2, Wt3, histBlocks);
    partition_kernel<<<(E + 8191) / 8192, 256, 0, stream>>>(row, col, bucketsize, gcur,
                                                            emid, E, NB);
    bucket_deg_kernel<<<NB, 256, 0, stream>>>(bucketsize, emid, rowptr, p1, p2,
                                              coeff, wself, N, NB);
    bucket_place_kernel<<<NB, 256, 0, stream>>>(bucketsize, emid, rowptr, coeff, epack, N);

    float* out = (float*)d_out;
    int gemmGrid = (N + 127) / 128;
    int aggGrid = (N + 3) / 4;
    // layer 1
    gemm_mfma<128, float><<<gemmGrid, 256, 0, stream>>>(x, Wt1, bufH, N);
    agg128_kernel<<<aggGrid, 256, 0, stream>>>((const __half2*)bufH, rowptr, epack, wself,
                                               b1, (__half2*)actH, N);
    // layer 2
    gemm_mfma<128, _Float16><<<gemmGrid, 256, 0, stream>>>(actH, Wt2, bufH, N);
    agg128_kernel<<<aggGrid, 256, 0, stream>>>((const __half2*)bufH, rowptr, epack, wself,
                                               b2, (__half2*)actH, N);
    // layer 3 (D_OUT=64, no relu)
    gemm_mfma<64, _Float16><<<gemmGrid, 256, 0, stream>>>(actH, Wt3, bufH, N);
    agg64_kernel<<<aggGrid, 256, 0, stream>>>((const __half*)bufH, rowptr, epack, wself,
                                              b3, out, N);
}